// Round 15
// baseline (314.138 us; speedup 1.0000x reference)
//
#include <hip/hip_runtime.h>
#include <hip/hip_bf16.h>

#define N_NODES 50000
#define N_EDGES 800000
#define F_IN    128
#define F_HID   128
#define F_OUT   40
#define N_TILES (N_NODES / 16)                // 3125 (exact)

#define NBIN      98                          // bins of 512 nodes (dst >> 9)
#define BIN_SHIFT 9
#define EPB       1024                        // edges per bin block
#define CAP       32                          // LDS slots per bin
#define GBIN_CAP  9216                        // global slots per bin

#define CVT_ELEMS (F_IN * F_HID + F_OUT * F_HID)         // 16384 + 5120 = 21504
#define CVT_BLOCKS (CVT_ELEMS / 256)                     // 84
#define BIN_BLOCKS ((N_EDGES + EPB - 1) / EPB)           // 782
#define G1_BLOCKS  ((N_TILES + 3) / 4)                   // 782

typedef __attribute__((ext_vector_type(8))) short bf16x8;   // 8 bf16 = 4 VGPRs
typedef __attribute__((ext_vector_type(4))) float f32x4;

__device__ __forceinline__ float2 unpack_bf2(unsigned u) {
    float2 r;
    r.x = __uint_as_float(u << 16);
    r.y = __uint_as_float(u & 0xffff0000u);
    return r;
}
__device__ __forceinline__ short bfraw(float v) {
    __hip_bfloat16 h = __float2bfloat16(v);
    return *(short*)&h;
}
__device__ __forceinline__ float bf16u_to_f32(unsigned short us) {
    return __uint_as_float(((unsigned)us) << 16);
}
__device__ __forceinline__ unsigned f32_to_h16(float v) {
    _Float16 h = (_Float16)v;
    return (unsigned)*(unsigned short*)&h;
}
__device__ __forceinline__ float h16_to_f32(unsigned bits) {
    unsigned short us = (unsigned short)bits;
    _Float16 h = *(_Float16*)&us;
    return (float)h;
}

__device__ __forceinline__ int ld_src(const unsigned int* w, int is64, int e) {
    return is64 ? (int)w[2 * e] : (int)w[e];
}
__device__ __forceinline__ int ld_dst(const unsigned int* w, int is64, int e) {
    return is64 ? (int)w[2 * (N_EDGES + e)] : (int)w[N_EDGES + e];
}

// ---- 1. init: blocks 0..83 convert W1 (bf16, transposed) and W2 (FP32, transposed);
//         block 84 sniffs index width and zeroes gcnt.
__global__ void k_init(const unsigned int* __restrict__ ew,
                       const float* __restrict__ W1, const float* __restrict__ W2,
                       __hip_bfloat16* __restrict__ w1t, float* __restrict__ w2tf,
                       int* __restrict__ flag, int* __restrict__ gcnt) {
    int b = blockIdx.x, t = threadIdx.x;
    if (b < CVT_BLOCKS) {
        int idx = b * 256 + t;
        if (idx < F_IN * F_HID) {
            int n = idx >> 7, k = idx & 127;
            w1t[idx] = __float2bfloat16(W1[k * F_HID + n]);
        } else {
            int j = idx - F_IN * F_HID;          // 0 .. 5119
            int n = j >> 7, k = j & 127;
            w2tf[j] = W2[k * F_OUT + n];         // [40][128] fp32 transposed
        }
        return;
    }
    __shared__ int nz;
    if (t == 0) nz = 0;
    __syncthreads();
    int local = 0;
    for (int i = t; i < 4096; i += 256)
        if (ew[2 * i + 1] != 0u) local = 1;
    if (local) atomicOr(&nz, 1);
    if (t < NBIN) gcnt[t] = 0;
    __syncthreads();
    if (t == 0) flag[0] = (nz == 0) ? 1 : 0;     // 1 => int64 layout
}

// ---- 2. merged: blocks [0,782) bin edges; blocks [782,1564) MFMA gemm1 (row-major h1b).
__global__ void k_bing1(const unsigned int* __restrict__ ew, const int* __restrict__ flag,
                        int* __restrict__ gcnt, unsigned* __restrict__ gbin,
                        const float* __restrict__ x, const __hip_bfloat16* __restrict__ w1t,
                        __hip_bfloat16* __restrict__ h1b) {
    __shared__ unsigned buf[NBIN][CAP];        // 12.5 KB (unused by gemm blocks)
    __shared__ int cnt[NBIN];
    __shared__ int base[NBIN];
    int t = threadIdx.x;
    if (blockIdx.x < BIN_BLOCKS) {
        for (int i = t; i < NBIN; i += 256) cnt[i] = 0;
        __syncthreads();
        int is64 = flag[0];
        int e0 = blockIdx.x * EPB;
        int n = min(EPB, N_EDGES - e0);
        for (int i = t; i < n; i += 256) {
            int e = e0 + i;
            int s = ld_src(ew, is64, e), d = ld_dst(ew, is64, e);
            unsigned rec = (unsigned)s | ((unsigned)d << 16);
            int b = d >> BIN_SHIFT;
            int c = atomicAdd(&cnt[b], 1);
            if (c < CAP) buf[b][c] = rec;
            else {
                int g = atomicAdd(&gcnt[b], 1);
                gbin[(size_t)b * GBIN_CAP + g] = rec;
            }
        }
        __syncthreads();
        if (t < NBIN) {
            int m = min(cnt[t], CAP);
            base[t] = atomicAdd(&gcnt[t], m);
            cnt[t] = m;
        }
        __syncthreads();
        int wave = t >> 6, lane = t & 63;
        for (int b = wave; b < NBIN; b += 4) {
            int m = cnt[b], bs = base[b];
            for (int i = lane; i < m; i += 64)
                gbin[(size_t)b * GBIN_CAP + bs + i] = buf[b][i];
        }
        return;
    }
    // ---- gemm1 part
    int wave = t >> 6, lane = t & 63;
    int tile = (blockIdx.x - BIN_BLOCKS) * 4 + wave;
    if (tile >= N_TILES) return;
    int node0 = tile * 16;
    int m = lane & 15, q = lane >> 4;
    bf16x8 A[4];
    const float* arow = x + (size_t)(node0 + m) * F_IN + q * 8;
#pragma unroll
    for (int kt = 0; kt < 4; kt++) {
        float4 f0 = *(const float4*)(arow + kt * 32);
        float4 f1 = *(const float4*)(arow + kt * 32 + 4);
        bf16x8 a;
        a[0] = bfraw(f0.x); a[1] = bfraw(f0.y); a[2] = bfraw(f0.z); a[3] = bfraw(f0.w);
        a[4] = bfraw(f1.x); a[5] = bfraw(f1.y); a[6] = bfraw(f1.z); a[7] = bfraw(f1.w);
        A[kt] = a;
    }
#pragma unroll
    for (int c = 0; c < 8; c++) {
        f32x4 acc = {0.f, 0.f, 0.f, 0.f};
        const __hip_bfloat16* brow = w1t + (size_t)(c * 16 + m) * F_IN + q * 8;
#pragma unroll
        for (int kt = 0; kt < 4; kt++) {
            bf16x8 B = *(const bf16x8*)(brow + kt * 32);
            acc = __builtin_amdgcn_mfma_f32_16x16x32_bf16(A[kt], B, acc, 0, 0, 0);
        }
#pragma unroll
        for (int r = 0; r < 4; r++)
            h1b[(size_t)(node0 + q * 4 + r) * F_HID + c * 16 + m] = __float2bfloat16(acc[r]);
    }
}

// ---- 3. passB1: per-bin node histogram + scan -> rowptr, dinv (one block per bin)
__global__ void k_passB1(const int* __restrict__ gcnt, const unsigned* __restrict__ gbin,
                         int* __restrict__ rowptr, float* __restrict__ dinv) {
    __shared__ int c[512];
    __shared__ int s2[256];
    __shared__ int gall[NBIN];
    __shared__ int bbase;
    int t = threadIdx.x;
    int b = blockIdx.x;
    c[t] = 0; c[t + 256] = 0;
    if (t < NBIN) gall[t] = gcnt[t];
    __syncthreads();
    if (t == 0) {
        int s = 0;
        for (int i = 0; i < b; i++) s += gall[i];
        bbase = s;
    }
    int n = gall[b];
    const unsigned* rec = gbin + (size_t)b * GBIN_CAP;
    int base512 = b << BIN_SHIFT;
    for (int i = t; i < n; i += 256)
        atomicAdd(&c[(int)(rec[i] >> 16) - base512], 1);
    __syncthreads();
    int a0 = c[2 * t], a1 = c[2 * t + 1];
    s2[t] = a0 + a1;
    __syncthreads();
    for (int off = 1; off < 256; off <<= 1) {
        int u = (t >= off) ? s2[t - off] : 0;
        __syncthreads();
        s2[t] += u;
        __syncthreads();
    }
    int ebase = bbase + s2[t] - a0 - a1;
    int i0 = base512 + 2 * t, i1 = i0 + 1;
    if (i0 < N_NODES) { rowptr[i0] = ebase;      dinv[i0] = rsqrtf((float)a0 + 1.f); }
    if (i1 < N_NODES) { rowptr[i1] = ebase + a0; dinv[i1] = rsqrtf((float)a1 + 1.f); }
    if (b == 0 && t == 0) rowptr[N_NODES] = N_EDGES;
}

// ---- 4. passB2: scatter bin records to final CSR slots (block-local dense window)
__global__ void k_passB2(const int* __restrict__ gcnt, const unsigned* __restrict__ gbin,
                         const int* __restrict__ rowptr, const float* __restrict__ dinv,
                         unsigned* __restrict__ srcw) {
    __shared__ int pos[512];
    __shared__ float dloc[512];
    int t = threadIdx.x;
    int b = blockIdx.x;
    int base512 = b << BIN_SHIFT;
#pragma unroll
    for (int k = 0; k < 2; k++) {
        int j = t + k * 256;
        int i = base512 + j;
        pos[j]  = (i < N_NODES) ? rowptr[i] : 0;
        dloc[j] = (i < N_NODES) ? dinv[i] : 0.f;
    }
    __syncthreads();
    int n = gcnt[b];
    const unsigned* rec = gbin + (size_t)b * GBIN_CAP;
    for (int i = t; i < n; i += 256) {
        unsigned r = rec[i];
        int s  = (int)(r & 0xFFFFu);
        int dl = (int)(r >> 16) - base512;
        int slot = atomicAdd(&pos[dl], 1);
        float norm = dinv[s] * dloc[dl];
        srcw[slot] = (unsigned)s | (f32_to_h16(norm) << 16);
    }
}

// ---- 5. FUSED layer-1 aggregate + relu + gemm2. Per block: 4 nodes aggregated
//         (scalar edge-record path, MLP=8 gathers), h1r rows staged fp32 in LDS
//         (no bf16 rounding of h1r), then 160 threads compute h2 = h1r @ W2
//         as fp32 dots against L1-resident w2tf. Writes only h2b (bf16).
__global__ void k_agg1g2(const int* __restrict__ rowptr, const unsigned* __restrict__ srcw,
                         const float* __restrict__ dinv, const __hip_bfloat16* __restrict__ h1b,
                         const float* __restrict__ b1, const float* __restrict__ w2tf,
                         __hip_bfloat16* __restrict__ h2b) {
    __shared__ float xs[4][F_HID];             // 2 KB
    int wave = threadIdx.x >> 6, lane = threadIdx.x & 63;
    int node = blockIdx.x * 4 + wave;
    float di = dinv[node];
    int beg = __builtin_amdgcn_readfirstlane(rowptr[node]);
    int end = __builtin_amdgcn_readfirstlane(rowptr[node + 1]);
    const unsigned* h1u = (const unsigned*)h1b;
    float2 acc = unpack_bf2(h1u[(size_t)node * 64 + lane]);
    float w0 = di * di;
    acc.x *= w0; acc.y *= w0;
    int e = beg;
    for (; e + 7 < end; e += 8) {
        unsigned p[8];
#pragma unroll
        for (int j = 0; j < 8; j++) p[j] = srcw[e + j];     // uniform addr -> s_load
        unsigned u[8];
#pragma unroll
        for (int j = 0; j < 8; j++)
            u[j] = h1u[(size_t)(p[j] & 0xFFFFu) * 64 + lane];
#pragma unroll
        for (int j = 0; j < 8; j++) {
            float w = h16_to_f32(p[j] >> 16);
            float2 v = unpack_bf2(u[j]);
            acc.x += v.x * w;
            acc.y += v.y * w;
        }
    }
    for (; e < end; e++) {
        unsigned p = srcw[e];
        float w = h16_to_f32(p >> 16);
        float2 v = unpack_bf2(h1u[(size_t)(p & 0xFFFFu) * 64 + lane]);
        acc.x += v.x * w;
        acc.y += v.y * w;
    }
    float2 bb = ((const float2*)b1)[lane];
    xs[wave][2 * lane]     = fmaxf(acc.x + bb.x, 0.f);
    xs[wave][2 * lane + 1] = fmaxf(acc.y + bb.y, 0.f);
    __syncthreads();
    // ---- gemm2 epilogue: thread -> (node nd, out col)
    int nd = threadIdx.x >> 6, col = threadIdx.x & 63;
    if (col < F_OUT) {
        const float4* wrow = (const float4*)(w2tf + col * F_HID);
        const float4* xrow = (const float4*)xs[nd];
        float s = 0.f;
#pragma unroll 8
        for (int k = 0; k < F_HID / 4; k++) {
            float4 a = xrow[k], w = wrow[k];
            s += a.x * w.x + a.y * w.y + a.z * w.z + a.w * w.w;
        }
        h2b[(size_t)(blockIdx.x * 4 + nd) * F_OUT + col] = __float2bfloat16(s);
    }
}

// ---- 6. fused layer-2 aggregate + self-loop + bias + log_softmax.
//         Scalar edge-record path; bf16 h2 gather.
__global__ void k_agg2f(const int* __restrict__ rowptr, const unsigned* __restrict__ srcw,
                        const float* __restrict__ dinv,
                        const unsigned short* __restrict__ h2b,
                        const float* __restrict__ b2, float* __restrict__ out) {
    int wave = threadIdx.x >> 6, lane = threadIdx.x & 63;
    int node = blockIdx.x * 4 + wave;
    float di = dinv[node];
    int beg = __builtin_amdgcn_readfirstlane(rowptr[node]);
    int end = __builtin_amdgcn_readfirstlane(rowptr[node + 1]);
    int l = (lane < F_OUT) ? lane : 0;
    float acc = bf16u_to_f32(h2b[(size_t)node * F_OUT + l]) * di * di;
    int e = beg;
    for (; e + 7 < end; e += 8) {
        unsigned p[8];
#pragma unroll
        for (int j = 0; j < 8; j++) p[j] = srcw[e + j];     // uniform addr -> s_load
        float v[8];
#pragma unroll
        for (int j = 0; j < 8; j++)
            v[j] = bf16u_to_f32(h2b[(size_t)(p[j] & 0xFFFFu) * F_OUT + l]);
#pragma unroll
        for (int j = 0; j < 8; j++)
            acc += v[j] * h16_to_f32(p[j] >> 16);
    }
    for (; e < end; e++) {
        unsigned p = srcw[e];
        acc += bf16u_to_f32(h2b[(size_t)(p & 0xFFFFu) * F_OUT + l]) * h16_to_f32(p >> 16);
    }
    float v = (lane < F_OUT) ? acc + b2[lane] : -INFINITY;
    float m = v;
    for (int off = 32; off; off >>= 1) m = fmaxf(m, __shfl_xor(m, off));
    float ex = (lane < F_OUT) ? __expf(v - m) : 0.f;
    float ssum = ex;
    for (int off = 32; off; off >>= 1) ssum += __shfl_xor(ssum, off);
    float ls = __logf(ssum);
    if (lane < F_OUT)
        out[(size_t)node * F_OUT + lane] = v - m - ls;
}

extern "C" void kernel_launch(void* const* d_in, const int* in_sizes, int n_in,
                              void* d_out, int out_size, void* d_ws, size_t ws_size,
                              hipStream_t stream) {
    const float* x  = (const float*)d_in[0];
    const float* W1 = (const float*)d_in[1];
    const float* b1 = (const float*)d_in[2];
    const float* W2 = (const float*)d_in[3];
    const float* b2 = (const float*)d_in[4];
    const unsigned int* ew = (const unsigned int*)d_in[5];
    float* out = (float*)d_out;

    // workspace (~24 MB)
    char* ws = (char*)d_ws;
    int*   flag     = (int*)ws;   ws += 256;
    int*   gcnt     = (int*)ws;   ws += 512;
    float* dinv     = (float*)ws; ws += ((N_NODES * 4 + 255) / 256) * 256;
    int*   rowptr   = (int*)ws;   ws += (((N_NODES + 1) * 4 + 255) / 256) * 256;
    unsigned* gbin  = (unsigned*)ws; ws += (size_t)NBIN * GBIN_CAP * 4;   // 3.6 MB
    unsigned* srcw  = (unsigned*)ws; ws += (size_t)N_EDGES * 4;           // 3.2 MB
    __hip_bfloat16* w1t = (__hip_bfloat16*)ws; ws += F_IN * F_HID * 2;
    float* w2tf = (float*)ws;     ws += F_OUT * F_HID * 4;                // 20 KB fp32
    __hip_bfloat16* h1b = (__hip_bfloat16*)ws; ws += (size_t)N_NODES * F_HID * 2;  // 12.8 MB
    __hip_bfloat16* h2b = (__hip_bfloat16*)ws; ws += (size_t)N_NODES * F_OUT * 2;  // 4 MB

    k_init   <<<CVT_BLOCKS + 1, 256, 0, stream>>>(ew, W1, W2, w1t, w2tf, flag, gcnt);
    k_bing1  <<<BIN_BLOCKS + G1_BLOCKS, 256, 0, stream>>>(ew, flag, gcnt, gbin, x, w1t, h1b);
    k_passB1 <<<NBIN, 256, 0, stream>>>(gcnt, gbin, rowptr, dinv);
    k_passB2 <<<NBIN, 256, 0, stream>>>(gcnt, gbin, rowptr, dinv, srcw);
    k_agg1g2 <<<N_NODES / 4, 256, 0, stream>>>(rowptr, srcw, dinv, h1b, b1, w2tf, h2b);
    k_agg2f  <<<N_NODES / 4, 256, 0, stream>>>(rowptr, srcw, dinv,
                                               (const unsigned short*)h2b, b2, out);
}

// Round 16
// 209.989 us; speedup vs baseline: 1.4960x; 1.4960x over previous
//
#include <hip/hip_runtime.h>
#include <hip/hip_bf16.h>

#define N_NODES 50000
#define N_EDGES 800000
#define F_IN    128
#define F_HID   128
#define F_OUT   40
#define N_TILES (N_NODES / 16)                // 3125 (exact)

#define NBIN      98                          // bins of 512 nodes (dst >> 9)
#define BIN_SHIFT 9
#define EPB       1024                        // edges per bin block
#define CAP       32                          // LDS slots per bin
#define GBIN_CAP  9216                        // global slots per bin

#define CVT_BLOCKS ((F_IN * F_HID + 48 * F_HID) / 256)   // 88
#define BIN_BLOCKS ((N_EDGES + EPB - 1) / EPB)           // 782
#define G1_BLOCKS  ((N_TILES + 3) / 4)                   // 782

typedef __attribute__((ext_vector_type(8))) short bf16x8;   // 8 bf16 = 4 VGPRs
typedef __attribute__((ext_vector_type(4))) float f32x4;

__device__ __forceinline__ float2 unpack_bf2(unsigned u) {
    float2 r;
    r.x = __uint_as_float(u << 16);
    r.y = __uint_as_float(u & 0xffff0000u);
    return r;
}
__device__ __forceinline__ unsigned pack_bf2(float x, float y) {
    union { unsigned u; __hip_bfloat16 h[2]; } cv;
    cv.h[0] = __float2bfloat16(x);
    cv.h[1] = __float2bfloat16(y);
    return cv.u;
}
__device__ __forceinline__ short bfraw(float v) {
    __hip_bfloat16 h = __float2bfloat16(v);
    return *(short*)&h;
}
__device__ __forceinline__ float bf16u_to_f32(unsigned short us) {
    return __uint_as_float(((unsigned)us) << 16);
}
__device__ __forceinline__ unsigned f32_to_h16(float v) {
    _Float16 h = (_Float16)v;
    return (unsigned)*(unsigned short*)&h;
}
__device__ __forceinline__ float h16_to_f32(unsigned bits) {
    unsigned short us = (unsigned short)bits;
    _Float16 h = *(_Float16*)&us;
    return (float)h;
}

__device__ __forceinline__ int ld_src(const unsigned int* w, int is64, int e) {
    return is64 ? (int)w[2 * e] : (int)w[e];
}
__device__ __forceinline__ int ld_dst(const unsigned int* w, int is64, int e) {
    return is64 ? (int)w[2 * (N_EDGES + e)] : (int)w[N_EDGES + e];
}

// ---- 1. init: blocks 0..87 convert W1/W2 to transposed bf16; block 88 sniffs
//         index width and zeroes gcnt.
__global__ void k_init(const unsigned int* __restrict__ ew,
                       const float* __restrict__ W1, const float* __restrict__ W2,
                       __hip_bfloat16* __restrict__ w1t, __hip_bfloat16* __restrict__ w2t,
                       int* __restrict__ flag, int* __restrict__ gcnt) {
    int b = blockIdx.x, t = threadIdx.x;
    if (b < CVT_BLOCKS) {
        int idx = b * 256 + t;
        if (idx < F_IN * F_HID) {
            int n = idx >> 7, k = idx & 127;
            w1t[idx] = __float2bfloat16(W1[k * F_HID + n]);
        } else {
            int j = idx - F_IN * F_HID;          // 0 .. 6143
            int n = j >> 7, k = j & 127;
            w2t[j] = __float2bfloat16(n < F_OUT ? W2[k * F_OUT + n] : 0.f);
        }
        return;
    }
    __shared__ int nz;
    if (t == 0) nz = 0;
    __syncthreads();
    int local = 0;
    for (int i = t; i < 4096; i += 256)
        if (ew[2 * i + 1] != 0u) local = 1;
    if (local) atomicOr(&nz, 1);
    if (t < NBIN) gcnt[t] = 0;
    __syncthreads();
    if (t == 0) flag[0] = (nz == 0) ? 1 : 0;     // 1 => int64 layout
}

// ---- 2. merged: blocks [0,782) bin edges; blocks [782,1564) MFMA gemm1 (row-major h1b).
__global__ void k_bing1(const unsigned int* __restrict__ ew, const int* __restrict__ flag,
                        int* __restrict__ gcnt, unsigned* __restrict__ gbin,
                        const float* __restrict__ x, const __hip_bfloat16* __restrict__ w1t,
                        __hip_bfloat16* __restrict__ h1b) {
    __shared__ unsigned buf[NBIN][CAP];        // 12.5 KB (unused by gemm blocks)
    __shared__ int cnt[NBIN];
    __shared__ int base[NBIN];
    int t = threadIdx.x;
    if (blockIdx.x < BIN_BLOCKS) {
        for (int i = t; i < NBIN; i += 256) cnt[i] = 0;
        __syncthreads();
        int is64 = flag[0];
        int e0 = blockIdx.x * EPB;
        int n = min(EPB, N_EDGES - e0);
        for (int i = t; i < n; i += 256) {
            int e = e0 + i;
            int s = ld_src(ew, is64, e), d = ld_dst(ew, is64, e);
            unsigned rec = (unsigned)s | ((unsigned)d << 16);
            int b = d >> BIN_SHIFT;
            int c = atomicAdd(&cnt[b], 1);
            if (c < CAP) buf[b][c] = rec;
            else {
                int g = atomicAdd(&gcnt[b], 1);
                gbin[(size_t)b * GBIN_CAP + g] = rec;
            }
        }
        __syncthreads();
        if (t < NBIN) {
            int m = min(cnt[t], CAP);
            base[t] = atomicAdd(&gcnt[t], m);
            cnt[t] = m;
        }
        __syncthreads();
        int wave = t >> 6, lane = t & 63;
        for (int b = wave; b < NBIN; b += 4) {
            int m = cnt[b], bs = base[b];
            for (int i = lane; i < m; i += 64)
                gbin[(size_t)b * GBIN_CAP + bs + i] = buf[b][i];
        }
        return;
    }
    // ---- gemm1 part
    int wave = t >> 6, lane = t & 63;
    int tile = (blockIdx.x - BIN_BLOCKS) * 4 + wave;
    if (tile >= N_TILES) return;
    int node0 = tile * 16;
    int m = lane & 15, q = lane >> 4;
    bf16x8 A[4];
    const float* arow = x + (size_t)(node0 + m) * F_IN + q * 8;
#pragma unroll
    for (int kt = 0; kt < 4; kt++) {
        float4 f0 = *(const float4*)(arow + kt * 32);
        float4 f1 = *(const float4*)(arow + kt * 32 + 4);
        bf16x8 a;
        a[0] = bfraw(f0.x); a[1] = bfraw(f0.y); a[2] = bfraw(f0.z); a[3] = bfraw(f0.w);
        a[4] = bfraw(f1.x); a[5] = bfraw(f1.y); a[6] = bfraw(f1.z); a[7] = bfraw(f1.w);
        A[kt] = a;
    }
#pragma unroll
    for (int c = 0; c < 8; c++) {
        f32x4 acc = {0.f, 0.f, 0.f, 0.f};
        const __hip_bfloat16* brow = w1t + (size_t)(c * 16 + m) * F_IN + q * 8;
#pragma unroll
        for (int kt = 0; kt < 4; kt++) {
            bf16x8 B = *(const bf16x8*)(brow + kt * 32);
            acc = __builtin_amdgcn_mfma_f32_16x16x32_bf16(A[kt], B, acc, 0, 0, 0);
        }
#pragma unroll
        for (int r = 0; r < 4; r++)
            h1b[(size_t)(node0 + q * 4 + r) * F_HID + c * 16 + m] = __float2bfloat16(acc[r]);
    }
}

// ---- 3. passB1: per-bin node histogram + scan -> rowptr, dinv (one block per bin)
__global__ void k_passB1(const int* __restrict__ gcnt, const unsigned* __restrict__ gbin,
                         int* __restrict__ rowptr, float* __restrict__ dinv) {
    __shared__ int c[512];
    __shared__ int s2[256];
    __shared__ int gall[NBIN];
    __shared__ int bbase;
    int t = threadIdx.x;
    int b = blockIdx.x;
    c[t] = 0; c[t + 256] = 0;
    if (t < NBIN) gall[t] = gcnt[t];
    __syncthreads();
    if (t == 0) {
        int s = 0;
        for (int i = 0; i < b; i++) s += gall[i];
        bbase = s;
    }
    int n = gall[b];
    const unsigned* rec = gbin + (size_t)b * GBIN_CAP;
    int base512 = b << BIN_SHIFT;
    for (int i = t; i < n; i += 256)
        atomicAdd(&c[(int)(rec[i] >> 16) - base512], 1);
    __syncthreads();
    int a0 = c[2 * t], a1 = c[2 * t + 1];
    s2[t] = a0 + a1;
    __syncthreads();
    for (int off = 1; off < 256; off <<= 1) {
        int u = (t >= off) ? s2[t - off] : 0;
        __syncthreads();
        s2[t] += u;
        __syncthreads();
    }
    int ebase = bbase + s2[t] - a0 - a1;
    int i0 = base512 + 2 * t, i1 = i0 + 1;
    if (i0 < N_NODES) { rowptr[i0] = ebase;      dinv[i0] = rsqrtf((float)a0 + 1.f); }
    if (i1 < N_NODES) { rowptr[i1] = ebase + a0; dinv[i1] = rsqrtf((float)a1 + 1.f); }
    if (b == 0 && t == 0) rowptr[N_NODES] = N_EDGES;
}

// ---- 4. passB2: scatter bin records to final CSR slots (block-local dense window)
__global__ void k_passB2(const int* __restrict__ gcnt, const unsigned* __restrict__ gbin,
                         const int* __restrict__ rowptr, const float* __restrict__ dinv,
                         unsigned* __restrict__ srcw) {
    __shared__ int pos[512];
    __shared__ float dloc[512];
    int t = threadIdx.x;
    int b = blockIdx.x;
    int base512 = b << BIN_SHIFT;
#pragma unroll
    for (int k = 0; k < 2; k++) {
        int j = t + k * 256;
        int i = base512 + j;
        pos[j]  = (i < N_NODES) ? rowptr[i] : 0;
        dloc[j] = (i < N_NODES) ? dinv[i] : 0.f;
    }
    __syncthreads();
    int n = gcnt[b];
    const unsigned* rec = gbin + (size_t)b * GBIN_CAP;
    for (int i = t; i < n; i += 256) {
        unsigned r = rec[i];
        int s  = (int)(r & 0xFFFFu);
        int dl = (int)(r >> 16) - base512;
        int slot = atomicAdd(&pos[dl], 1);
        float norm = dinv[s] * dloc[dl];
        srcw[slot] = (unsigned)s | (f32_to_h16(norm) << 16);
    }
}

// ---- 5. fused layer-1 aggregate + self-loop + bias + relu.
//         Edge records loaded via SCALAR path (readfirstlane'd uniform indices
//         -> s_load through constant cache), 8 records per batch; row-gathers
//         issue back-to-back with MLP=8.
__global__ void k_agg1f(const int* __restrict__ rowptr, const unsigned* __restrict__ srcw,
                        const float* __restrict__ dinv, const __hip_bfloat16* __restrict__ h1b,
                        const float* __restrict__ b1, __hip_bfloat16* __restrict__ h1rb) {
    int wave = threadIdx.x >> 6, lane = threadIdx.x & 63;
    int node = blockIdx.x * 4 + wave;
    float di = dinv[node];
    int beg = __builtin_amdgcn_readfirstlane(rowptr[node]);
    int end = __builtin_amdgcn_readfirstlane(rowptr[node + 1]);
    const unsigned* h1u = (const unsigned*)h1b;
    float2 acc = unpack_bf2(h1u[(size_t)node * 64 + lane]);
    float w0 = di * di;
    acc.x *= w0; acc.y *= w0;
    int e = beg;
    for (; e + 7 < end; e += 8) {
        unsigned p[8];
#pragma unroll
        for (int j = 0; j < 8; j++) p[j] = srcw[e + j];     // uniform addr -> s_load
        unsigned u[8];
#pragma unroll
        for (int j = 0; j < 8; j++)
            u[j] = h1u[(size_t)(p[j] & 0xFFFFu) * 64 + lane];
#pragma unroll
        for (int j = 0; j < 8; j++) {
            float w = h16_to_f32(p[j] >> 16);
            float2 v = unpack_bf2(u[j]);
            acc.x += v.x * w;
            acc.y += v.y * w;
        }
    }
    for (; e < end; e++) {
        unsigned p = srcw[e];
        float w = h16_to_f32(p >> 16);
        float2 v = unpack_bf2(h1u[(size_t)(p & 0xFFFFu) * 64 + lane]);
        acc.x += v.x * w;
        acc.y += v.y * w;
    }
    float2 bb = ((const float2*)b1)[lane];
    acc.x = fmaxf(acc.x + bb.x, 0.f);
    acc.y = fmaxf(acc.y + bb.y, 0.f);
    ((unsigned*)h1rb)[(size_t)node * 64 + lane] = pack_bf2(acc.x, acc.y);
}

// ---- 6. h2 = h1r @ W2 via MFMA (N padded 40->48). h2 out BF16.
__global__ void k_gemm2m(const __hip_bfloat16* __restrict__ h1rb,
                         const __hip_bfloat16* __restrict__ w2t,
                         __hip_bfloat16* __restrict__ h2b) {
    int wave = threadIdx.x >> 6, lane = threadIdx.x & 63;
    int tile = blockIdx.x * 4 + wave;
    if (tile >= N_TILES) return;
    int node0 = tile * 16;
    int m = lane & 15, q = lane >> 4;
    bf16x8 A[4];
    const __hip_bfloat16* arow = h1rb + (size_t)(node0 + m) * F_HID + q * 8;
#pragma unroll
    for (int kt = 0; kt < 4; kt++)
        A[kt] = *(const bf16x8*)(arow + kt * 32);
#pragma unroll
    for (int c = 0; c < 3; c++) {
        f32x4 acc = {0.f, 0.f, 0.f, 0.f};
        const __hip_bfloat16* brow = w2t + (size_t)(c * 16 + m) * F_HID + q * 8;
#pragma unroll
        for (int kt = 0; kt < 4; kt++) {
            bf16x8 B = *(const bf16x8*)(brow + kt * 32);
            acc = __builtin_amdgcn_mfma_f32_16x16x32_bf16(A[kt], B, acc, 0, 0, 0);
        }
        int col = c * 16 + m;
        if (col < F_OUT) {
#pragma unroll
            for (int r = 0; r < 4; r++)
                h2b[(size_t)(node0 + q * 4 + r) * F_OUT + col] = __float2bfloat16(acc[r]);
        }
    }
}

// ---- 7. fused layer-2 aggregate + self-loop + bias + log_softmax.
//         Same scalar edge-record path; bf16 h2 gather.
__global__ void k_agg2f(const int* __restrict__ rowptr, const unsigned* __restrict__ srcw,
                        const float* __restrict__ dinv,
                        const unsigned short* __restrict__ h2b,
                        const float* __restrict__ b2, float* __restrict__ out) {
    int wave = threadIdx.x >> 6, lane = threadIdx.x & 63;
    int node = blockIdx.x * 4 + wave;
    float di = dinv[node];
    int beg = __builtin_amdgcn_readfirstlane(rowptr[node]);
    int end = __builtin_amdgcn_readfirstlane(rowptr[node + 1]);
    int l = (lane < F_OUT) ? lane : 0;
    float acc = bf16u_to_f32(h2b[(size_t)node * F_OUT + l]) * di * di;
    int e = beg;
    for (; e + 7 < end; e += 8) {
        unsigned p[8];
#pragma unroll
        for (int j = 0; j < 8; j++) p[j] = srcw[e + j];     // uniform addr -> s_load
        float v[8];
#pragma unroll
        for (int j = 0; j < 8; j++)
            v[j] = bf16u_to_f32(h2b[(size_t)(p[j] & 0xFFFFu) * F_OUT + l]);
#pragma unroll
        for (int j = 0; j < 8; j++)
            acc += v[j] * h16_to_f32(p[j] >> 16);
    }
    for (; e < end; e++) {
        unsigned p = srcw[e];
        acc += bf16u_to_f32(h2b[(size_t)(p & 0xFFFFu) * F_OUT + l]) * h16_to_f32(p >> 16);
    }
    float v = (lane < F_OUT) ? acc + b2[lane] : -INFINITY;
    float m = v;
    for (int off = 32; off; off >>= 1) m = fmaxf(m, __shfl_xor(m, off));
    float ex = (lane < F_OUT) ? __expf(v - m) : 0.f;
    float ssum = ex;
    for (int off = 32; off; off >>= 1) ssum += __shfl_xor(ssum, off);
    float ls = __logf(ssum);
    if (lane < F_OUT)
        out[(size_t)node * F_OUT + lane] = v - m - ls;
}

extern "C" void kernel_launch(void* const* d_in, const int* in_sizes, int n_in,
                              void* d_out, int out_size, void* d_ws, size_t ws_size,
                              hipStream_t stream) {
    const float* x  = (const float*)d_in[0];
    const float* W1 = (const float*)d_in[1];
    const float* b1 = (const float*)d_in[2];
    const float* W2 = (const float*)d_in[3];
    const float* b2 = (const float*)d_in[4];
    const unsigned int* ew = (const unsigned int*)d_in[5];
    float* out = (float*)d_out;

    // workspace (~37 MB)
    char* ws = (char*)d_ws;
    int*   flag     = (int*)ws;   ws += 256;
    int*   gcnt     = (int*)ws;   ws += 512;
    float* dinv     = (float*)ws; ws += ((N_NODES * 4 + 255) / 256) * 256;
    int*   rowptr   = (int*)ws;   ws += (((N_NODES + 1) * 4 + 255) / 256) * 256;
    unsigned* gbin  = (unsigned*)ws; ws += (size_t)NBIN * GBIN_CAP * 4;   // 3.6 MB
    unsigned* srcw  = (unsigned*)ws; ws += (size_t)N_EDGES * 4;           // 3.2 MB
    __hip_bfloat16* w1t  = (__hip_bfloat16*)ws; ws += F_IN * F_HID * 2;
    __hip_bfloat16* w2t  = (__hip_bfloat16*)ws; ws += 48 * F_HID * 2;
    __hip_bfloat16* h1b  = (__hip_bfloat16*)ws; ws += (size_t)N_NODES * F_HID * 2;  // row-major
    __hip_bfloat16* h1rb = (__hip_bfloat16*)ws; ws += (size_t)N_NODES * F_HID * 2;  // row-major
    __hip_bfloat16* h2b  = (__hip_bfloat16*)ws; ws += (size_t)N_NODES * F_OUT * 2;

    k_init   <<<CVT_BLOCKS + 1, 256, 0, stream>>>(ew, W1, W2, w1t, w2t, flag, gcnt);
    k_bing1  <<<BIN_BLOCKS + G1_BLOCKS, 256, 0, stream>>>(ew, flag, gcnt, gbin, x, w1t, h1b);
    k_passB1 <<<NBIN, 256, 0, stream>>>(gcnt, gbin, rowptr, dinv);
    k_passB2 <<<NBIN, 256, 0, stream>>>(gcnt, gbin, rowptr, dinv, srcw);
    k_agg1f  <<<N_NODES / 4, 256, 0, stream>>>(rowptr, srcw, dinv, h1b, b1, h1rb);
    k_gemm2m <<<(N_TILES + 3) / 4, 256, 0, stream>>>(h1rb, w2t, h2b);
    k_agg2f  <<<N_NODES / 4, 256, 0, stream>>>(rowptr, srcw, dinv,
                                               (const unsigned short*)h2b, b2, out);
}